// Round 22
// baseline (678.236 us; speedup 1.0000x reference)
//
#include <hip/hip_runtime.h>
#include <hip/hip_fp8.h>
#include <hip/hip_cooperative_groups.h>

namespace cg = cooperative_groups;

#define NN 50000
#define DIM 64
#define NE 1250000

// ---- counting-sort CSR build: 64 edge-slices x 8 row-ranges = 512 blocks
#define NSL 64
#define SLICEB 19532          // ceil(NE / NSL); 19532*64 = 1250048 >= NE
#define RANGE 6250            // NN / 8 rows per range
#define CSTRIDE 50048         // padded row stride of cnt matrix

typedef __attribute__((ext_vector_type(2))) float f32x2;

// bf16 helpers (RNE pack, cheap unpack)
__device__ __forceinline__ unsigned short f2b(float f) {
    unsigned int b = __builtin_bit_cast(unsigned int, f);
    b = (b + 0x7fffu + ((b >> 16) & 1u)) >> 16;
    return (unsigned short)b;
}
__device__ __forceinline__ float blo(unsigned int u) {
    return __builtin_bit_cast(float, u << 16);
}
__device__ __forceinline__ float bhi(unsigned int u) {
    return __builtin_bit_cast(float, u & 0xffff0000u);
}

// fp8 e4m3 (OCP) helpers — hardware cvt on gfx950; word-select must be constant.
template <bool HI>
__device__ __forceinline__ f32x2 dec2(unsigned int u) {
#if __has_builtin(__builtin_amdgcn_cvt_pk_f32_fp8)
    return __builtin_amdgcn_cvt_pk_f32_fp8(u, HI);
#else
    unsigned int b0 = HI ? ((u >> 16) & 0xff) : (u & 0xff);
    unsigned int b1 = HI ? ((u >> 24) & 0xff) : ((u >> 8) & 0xff);
    __hip_fp8_e4m3 t0, t1;
    t0.__x = (unsigned char)b0;
    t1.__x = (unsigned char)b1;
    f32x2 r;
    r[0] = (float)t0;
    r[1] = (float)t1;
    return r;
#endif
}
__device__ __forceinline__ unsigned int enc4(float v0, float v1, float v2, float v3) {
#if __has_builtin(__builtin_amdgcn_cvt_pk_fp8_f32)
    unsigned int r = 0;
    r = __builtin_amdgcn_cvt_pk_fp8_f32(v0, v1, r, false);
    r = __builtin_amdgcn_cvt_pk_fp8_f32(v2, v3, r, true);
    return r;
#else
    __hip_fp8_e4m3 t0(v0), t1(v1), t2(v2), t3(v3);
    return (unsigned int)t0.__x | ((unsigned int)t1.__x << 8) |
           ((unsigned int)t2.__x << 16) | ((unsigned int)t3.__x << 24);
#endif
}

// ================= fused CSR build (cooperative, 512 x 1024) =================
// Phase 1 : per-(slice,range) histogram + bucket staging (r21's k_hist)
//           + fp8 cvt side-job (independent, overlaps)
// Phase 2 : per-row scan over slices (cnt -> within-row offsets) + block scan
// Phase 3 : block-prefix + offs write (scan_top+scan_final, local recompute)
// Phase 4 : CSR fill from staged buckets via LDS cursors (r21's k_fillb)
// Co-residency: 512 blocks = 2/CU exactly; 25 KB LDS -> 50 KB/CU; VGPR<=64
// via launch_bounds(1024,8). grid.sync() at the 3 dependence points.
__global__ __launch_bounds__(1024, 8) void k_build(
        const int* __restrict__ row, const int* __restrict__ col,
        const float* __restrict__ emb, unsigned char* __restrict__ x08,
        unsigned short* __restrict__ cnt, unsigned int* __restrict__ stage,
        int* __restrict__ bsize, int* __restrict__ partial,
        int* __restrict__ offs, int* __restrict__ csr) {
    cg::grid_group grid = cg::this_grid();
    __shared__ int h[RANGE];       // 25 KB, reused every phase
    __shared__ int bcnt;
    __shared__ int bpre_s;
    int bid = blockIdx.x;
    int tid = threadIdx.x;

    // ---------- phase 1: hist + stage ----------
    {
        int s   = (bid & 7) | ((bid >> 6) << 3);   // bid%8==s%8: slice on one XCD
        int rng = (bid >> 3) & 7;
        int lo = rng * RANGE;
        for (int i = tid; i < RANGE; i += 1024) h[i] = 0;
        if (tid == 0) bcnt = 0;
        __syncthreads();
        int beg = s * SLICEB;
        int end = beg + SLICEB;
        if (end > NE) end = NE;
        unsigned int* st = stage + (size_t)(s * 8 + rng) * SLICEB;
        int lane = tid & 63;
        for (int e = beg + tid; e < end; e += 1024) {
            int r = row[e] - lo;
            bool ok = (unsigned)r < RANGE;
            unsigned long long mask = __ballot(ok);
            if (ok) {
                int leader = __ffsll((long long)mask) - 1;
                int base = 0;
                if (lane == leader) base = atomicAdd(&bcnt, __popcll(mask));
                base = __shfl(base, leader);
                int off = __popcll(mask & ((1ull << lane) - 1ull));
                st[base + off] = ((unsigned int)r << 16) | (unsigned int)col[e];
                atomicAdd(&h[r], 1);  // LDS atomic
            }
        }
        __syncthreads();
        unsigned short* c = cnt + s * CSTRIDE + lo;
        for (int i = tid; i < RANGE; i += 1024) c[i] = (unsigned short)h[i];
        if (tid == 0) bsize[s * 8 + rng] = bcnt;
        // ----- phase 1b: fp8 cvt side-job (independent of hist) -----
        for (int t = bid * 1024 + tid; t < NN * DIM / 8; t += 512 * 1024) {
            const float4* p = (const float4*)emb + t * 2;
            float4 a = p[0], b = p[1];
            uint2 pk;
            pk.x = enc4(a.x, a.y, a.z, a.w);
            pk.y = enc4(b.x, b.y, b.z, b.w);
            ((uint2*)x08)[t] = pk;
        }
    }
    __threadfence();
    grid.sync();

    // ---------- phase 2: rowscan + block inclusive scan ----------
    int gt = bid * 1024 + tid;     // row id
    int acc = 0;
    if (gt < NN) {
#pragma unroll
        for (int s2 = 0; s2 < NSL; ++s2) {
            int c = cnt[s2 * CSTRIDE + gt];
            cnt[s2 * CSTRIDE + gt] = (unsigned short)acc;  // within-row excl offset
            acc += c;
        }
    }
    __syncthreads();               // h[] free again
    h[tid] = acc;
    __syncthreads();
    for (int off = 1; off < 1024; off <<= 1) {
        int x = (tid >= off) ? h[tid - off] : 0;
        __syncthreads();
        h[tid] += x;
        __syncthreads();
    }
    int incl = h[tid];
    if (tid == 1023) partial[bid] = incl;  // block total (0 for blocks >= 49)
    __threadfence();
    grid.sync();

    // ---------- phase 3: block prefix + offs ----------
    if (tid == 0) {
        int p = 0;
        for (int j = 0; j < bid && j < 49; ++j) p += partial[j];
        bpre_s = p;
    }
    __syncthreads();
    int bpre = bpre_s;
    if (gt < NN) offs[gt] = bpre + incl - acc;
    if (gt == NN - 1) offs[NN] = bpre + incl;  // == NE
    __threadfence();
    grid.sync();

    // ---------- phase 4: fill from staged buckets ----------
    {
        int s4   = bid >> 3;        // bid%8 == rng: range's csr region on one XCD
        int rng4 = bid & 7;
        int lo4 = rng4 * RANGE;
        const unsigned short* c4 = cnt + s4 * CSTRIDE + lo4;
        const int* o4 = offs + lo4;
        __syncthreads();            // h[] free again
        for (int i = tid; i < RANGE; i += 1024) h[i] = o4[i] + c4[i];
        __syncthreads();
        int nb = bsize[s4 * 8 + rng4];
        const unsigned int* st4 = stage + (size_t)(s4 * 8 + rng4) * SLICEB;
        for (int i = tid; i < nb; i += 1024) {
            unsigned int pk = st4[i];
            int r = pk >> 16;
            int pos = atomicAdd(&h[r], 1);  // LDS cursor
            csr[pos] = (int)(pk & 0xffffu);
        }
    }
}

// ---------------- one propagation layer (fp8 gather, fp32 accum) ----------------
// 8 nodes per wave: lane>>3 = node in wave, lane&7 = feature-octet.
// Gather source: fp8 mirror (3.2 MB, per-XCD-L2-resident, 64 B/edge).
// bf16 copies kept ONLY for final out-assembly (fp8 error doesn't compound).
template <int PHASE>
__global__ __launch_bounds__(256) void k_layer(const unsigned char* __restrict__ xin8,
                                               const float* __restrict__ emb,
                                               const unsigned short* __restrict__ xa16,
                                               const unsigned short* __restrict__ xb16,
                                               unsigned short* __restrict__ xout16,
                                               unsigned char* __restrict__ xout8,
                                               float* __restrict__ out,
                                               const int* __restrict__ offs,
                                               const int* __restrict__ csr) {
    int wid = (blockIdx.x * blockDim.x + threadIdx.x) >> 6;
    int lane = threadIdx.x & 63;
    int sub = lane >> 3;    // node within wave (0..7)
    int sl = lane & 7;      // feature-octet index (0..7)
    int n = 8 * wid + sub;
    if (n >= NN) return;
    int beg = offs[n];
    int end = offs[n + 1];
    const unsigned char* xq = xin8 + sl * 8;  // + c*64 bytes per neighbor

    float a0 = 0.f, a1 = 0.f, a2 = 0.f, a3 = 0.f, a4 = 0.f, a5 = 0.f, a6 = 0.f, a7 = 0.f;
    float b0 = 0.f, b1 = 0.f, b2 = 0.f, b3 = 0.f, b4 = 0.f, b5 = 0.f, b6 = 0.f, b7 = 0.f;
    int e = beg;
    for (; e + 8 <= end; e += 8) {
        int c0 = csr[e + 0], c1 = csr[e + 1], c2 = csr[e + 2], c3 = csr[e + 3];
        int c4 = csr[e + 4], c5 = csr[e + 5], c6 = csr[e + 6], c7 = csr[e + 7];
        uint2 u0 = *(const uint2*)(xq + c0 * 64);
        uint2 u1 = *(const uint2*)(xq + c1 * 64);
        uint2 u2 = *(const uint2*)(xq + c2 * 64);
        uint2 u3 = *(const uint2*)(xq + c3 * 64);
        uint2 u4 = *(const uint2*)(xq + c4 * 64);
        uint2 u5 = *(const uint2*)(xq + c5 * 64);
        uint2 u6 = *(const uint2*)(xq + c6 * 64);
        uint2 u7 = *(const uint2*)(xq + c7 * 64);
        f32x2 p;
        p = dec2<false>(u0.x); a0 += p[0]; a1 += p[1];
        p = dec2<true >(u0.x); a2 += p[0]; a3 += p[1];
        p = dec2<false>(u0.y); a4 += p[0]; a5 += p[1];
        p = dec2<true >(u0.y); a6 += p[0]; a7 += p[1];
        p = dec2<false>(u1.x); b0 += p[0]; b1 += p[1];
        p = dec2<true >(u1.x); b2 += p[0]; b3 += p[1];
        p = dec2<false>(u1.y); b4 += p[0]; b5 += p[1];
        p = dec2<true >(u1.y); b6 += p[0]; b7 += p[1];
        p = dec2<false>(u2.x); a0 += p[0]; a1 += p[1];
        p = dec2<true >(u2.x); a2 += p[0]; a3 += p[1];
        p = dec2<false>(u2.y); a4 += p[0]; a5 += p[1];
        p = dec2<true >(u2.y); a6 += p[0]; a7 += p[1];
        p = dec2<false>(u3.x); b0 += p[0]; b1 += p[1];
        p = dec2<true >(u3.x); b2 += p[0]; b3 += p[1];
        p = dec2<false>(u3.y); b4 += p[0]; b5 += p[1];
        p = dec2<true >(u3.y); b6 += p[0]; b7 += p[1];
        p = dec2<false>(u4.x); a0 += p[0]; a1 += p[1];
        p = dec2<true >(u4.x); a2 += p[0]; a3 += p[1];
        p = dec2<false>(u4.y); a4 += p[0]; a5 += p[1];
        p = dec2<true >(u4.y); a6 += p[0]; a7 += p[1];
        p = dec2<false>(u5.x); b0 += p[0]; b1 += p[1];
        p = dec2<true >(u5.x); b2 += p[0]; b3 += p[1];
        p = dec2<false>(u5.y); b4 += p[0]; b5 += p[1];
        p = dec2<true >(u5.y); b6 += p[0]; b7 += p[1];
        p = dec2<false>(u6.x); a0 += p[0]; a1 += p[1];
        p = dec2<true >(u6.x); a2 += p[0]; a3 += p[1];
        p = dec2<false>(u6.y); a4 += p[0]; a5 += p[1];
        p = dec2<true >(u6.y); a6 += p[0]; a7 += p[1];
        p = dec2<false>(u7.x); b0 += p[0]; b1 += p[1];
        p = dec2<true >(u7.x); b2 += p[0]; b3 += p[1];
        p = dec2<false>(u7.y); b4 += p[0]; b5 += p[1];
        p = dec2<true >(u7.y); b6 += p[0]; b7 += p[1];
    }
    for (; e < end; ++e) {
        uint2 u = *(const uint2*)(xq + csr[e] * 64);
        f32x2 p;
        p = dec2<false>(u.x); a0 += p[0]; a1 += p[1];
        p = dec2<true >(u.x); a2 += p[0]; a3 += p[1];
        p = dec2<false>(u.y); a4 += p[0]; a5 += p[1];
        p = dec2<true >(u.y); a6 += p[0]; a7 += p[1];
    }

    int d = end - beg;
    float inv = (d > 0) ? 1.0f / (float)d : 0.0f;
    float v0 = (a0 + b0) * inv;
    float v1 = (a1 + b1) * inv;
    float v2 = (a2 + b2) * inv;
    float v3 = (a3 + b3) * inv;
    float v4 = (a4 + b4) * inv;
    float v5 = (a5 + b5) * inv;
    float v6 = (a6 + b6) * inv;
    float v7 = (a7 + b7) * inv;

    int o = n * DIM + sl * 8;
    if (PHASE < 2) {
        uint4 pk16 = {(unsigned int)f2b(v0) | ((unsigned int)f2b(v1) << 16),
                      (unsigned int)f2b(v2) | ((unsigned int)f2b(v3) << 16),
                      (unsigned int)f2b(v4) | ((unsigned int)f2b(v5) << 16),
                      (unsigned int)f2b(v6) | ((unsigned int)f2b(v7) << 16)};
        *(uint4*)(xout16 + o) = pk16;
        uint2 pk8;
        pk8.x = enc4(v0, v1, v2, v3);
        pk8.y = enc4(v4, v5, v6, v7);
        *(uint2*)(xout8 + o) = pk8;
    } else {
        float4 e0 = *(const float4*)(emb + o);
        float4 e1 = *(const float4*)(emb + o + 4);
        uint4 ua = *(const uint4*)(xa16 + o);
        uint4 ub = *(const uint4*)(xb16 + o);
        float4 o0, o1;
        o0.x = 0.25f * (e0.x + blo(ua.x) + blo(ub.x) + v0);
        o0.y = 0.25f * (e0.y + bhi(ua.x) + bhi(ub.x) + v1);
        o0.z = 0.25f * (e0.z + blo(ua.y) + blo(ub.y) + v2);
        o0.w = 0.25f * (e0.w + bhi(ua.y) + bhi(ub.y) + v3);
        o1.x = 0.25f * (e1.x + blo(ua.z) + blo(ub.z) + v4);
        o1.y = 0.25f * (e1.y + bhi(ua.z) + bhi(ub.z) + v5);
        o1.z = 0.25f * (e1.z + blo(ua.w) + blo(ub.w) + v6);
        o1.w = 0.25f * (e1.w + bhi(ua.w) + bhi(ub.w) + v7);
        *(float4*)(out + o) = o0;
        *(float4*)(out + o + 4) = o1;
    }
}

extern "C" void kernel_launch(void* const* d_in, const int* in_sizes, int n_in,
                              void* d_out, int out_size, void* d_ws, size_t ws_size,
                              hipStream_t stream) {
    const int* edge = (const int*)d_in[0];
    const int* row = edge;        // edge_index[0]
    const int* col = edge + NE;   // edge_index[1]
    const float* emb = (const float*)d_in[1];
    float* out = (float*)d_out;

    // workspace layout (~75 MB of 256 MB)
    int* offs   = (int*)d_ws;                                // 50112 ints
    int* partial= offs + 50112;                              // 512 ints (pad 576)
    int* bsize  = partial + 576;                             // 512 ints (pad 576)
    int* csr    = bsize + 576;                               // 1250048 ints
    unsigned short* cnt = (unsigned short*)(csr + 1250048);  // 64*50048 ushort (6.4MB)
    unsigned short* xa16 = cnt + (size_t)NSL * CSTRIDE;      // 3.2M ushort
    unsigned short* xb16 = xa16 + NN * DIM;                  // 3.2M ushort
    unsigned char* x08 = (unsigned char*)(xb16 + NN * DIM);  // 3.2M bytes
    unsigned char* xa8 = x08 + NN * DIM;                     // 3.2M bytes
    unsigned char* xb8 = xa8 + NN * DIM;                     // 3.2M bytes
    unsigned int* stage = (unsigned int*)(xb8 + NN * DIM);   // 512*19532 uints (40MB)

    void* args[] = {(void*)&row, (void*)&col, (void*)&emb, (void*)&x08,
                    (void*)&cnt, (void*)&stage, (void*)&bsize, (void*)&partial,
                    (void*)&offs, (void*)&csr};
    hipLaunchCooperativeKernel((void*)k_build, dim3(512), dim3(1024), args, 0, stream);

    // 8 nodes per wave: 6250 waves -> 1563 blocks of 256 (guard in-kernel)
    int layer_blocks = 1563;
    k_layer<0><<<layer_blocks, 256, 0, stream>>>(x08, nullptr, nullptr, nullptr, xa16, xa8, nullptr, offs, csr);
    k_layer<1><<<layer_blocks, 256, 0, stream>>>(xa8, nullptr, nullptr, nullptr, xb16, xb8, nullptr, offs, csr);
    k_layer<2><<<layer_blocks, 256, 0, stream>>>(xb8, emb, xa16, xb16, nullptr, nullptr, out, offs, csr);
}

// Round 24
// 96.962 us; speedup vs baseline: 6.9949x; 6.9949x over previous
//
#include <hip/hip_runtime.h>
#include <hip/hip_fp8.h>

#define NN 50000
#define DIM 64
#define NE 1250000
#define NPARTS 196  // ceil(50000/256)

// ---- counting-sort CSR build: 64 edge-slices x 8 row-ranges = 512 blocks
#define NSL 64
#define SLICEB 19532          // ceil(NE / NSL); 19532*64 = 1250048 >= NE
#define RANGE 6250            // NN / 8 rows per range
#define CSTRIDE 50048         // padded row stride of cnt matrix

typedef __attribute__((ext_vector_type(2))) float f32x2;

// bf16 helpers (RNE pack, cheap unpack)
__device__ __forceinline__ unsigned short f2b(float f) {
    unsigned int b = __builtin_bit_cast(unsigned int, f);
    b = (b + 0x7fffu + ((b >> 16) & 1u)) >> 16;
    return (unsigned short)b;
}
__device__ __forceinline__ float blo(unsigned int u) {
    return __builtin_bit_cast(float, u << 16);
}
__device__ __forceinline__ float bhi(unsigned int u) {
    return __builtin_bit_cast(float, u & 0xffff0000u);
}

// fp8 e4m3 (OCP) helpers — hardware cvt on gfx950; word-select must be constant.
template <bool HI>
__device__ __forceinline__ f32x2 dec2(unsigned int u) {
#if __has_builtin(__builtin_amdgcn_cvt_pk_f32_fp8)
    return __builtin_amdgcn_cvt_pk_f32_fp8(u, HI);
#else
    unsigned int b0 = HI ? ((u >> 16) & 0xff) : (u & 0xff);
    unsigned int b1 = HI ? ((u >> 24) & 0xff) : ((u >> 8) & 0xff);
    __hip_fp8_e4m3 t0, t1;
    t0.__x = (unsigned char)b0;
    t1.__x = (unsigned char)b1;
    f32x2 r;
    r[0] = (float)t0;
    r[1] = (float)t1;
    return r;
#endif
}
__device__ __forceinline__ unsigned int enc4(float v0, float v1, float v2, float v3) {
#if __has_builtin(__builtin_amdgcn_cvt_pk_fp8_f32)
    unsigned int r = 0;
    r = __builtin_amdgcn_cvt_pk_fp8_f32(v0, v1, r, false);
    r = __builtin_amdgcn_cvt_pk_fp8_f32(v2, v3, r, true);
    return r;
#else
    __hip_fp8_e4m3 t0(v0), t1(v1), t2(v2), t3(v3);
    return (unsigned int)t0.__x | ((unsigned int)t1.__x << 8) |
           ((unsigned int)t2.__x << 16) | ((unsigned int)t3.__x << 24);
#endif
}

// ---------------- hist + bucket staging + fp8 cvt side-job ----------------
// bid -> slice s = (bid&7)|((bid>>6)<<3), rng = (bid>>3)&7 (bid%8 == s%8:
// same-slice blocks co-scheduled on one XCD -> slice read into L2 once).
// Stages each in-range edge as packed (r-lo)<<16 | col into bucket
// (s*8+rng)*SLICEB via wave-aggregated ballot append (one LDS atomic/wave).
// The fp8 cvt of emb rides along as an independent tail job (saves a launch;
// NO new sync semantics — r22's grid.sync coherence-spin cost ~200us/sync).
__global__ __launch_bounds__(1024) void k_hist(const int* __restrict__ row,
                                               const int* __restrict__ col,
                                               const float* __restrict__ emb,
                                               unsigned char* __restrict__ x08,
                                               unsigned short* __restrict__ cnt,
                                               unsigned int* __restrict__ stage,
                                               int* __restrict__ bsize) {
    __shared__ int h[RANGE];
    __shared__ int bcnt;
    int bid = blockIdx.x;
    int s   = (bid & 7) | ((bid >> 6) << 3);
    int rng = (bid >> 3) & 7;
    int lo = rng * RANGE;
    int tid = threadIdx.x;
    for (int i = tid; i < RANGE; i += 1024) h[i] = 0;
    if (tid == 0) bcnt = 0;
    __syncthreads();
    int beg = s * SLICEB;
    int end = beg + SLICEB;
    if (end > NE) end = NE;
    unsigned int* st = stage + (size_t)(s * 8 + rng) * SLICEB;
    int lane = tid & 63;
    for (int e = beg + tid; e < end; e += 1024) {
        int r = row[e] - lo;
        bool ok = (unsigned)r < RANGE;
        unsigned long long mask = __ballot(ok);
        if (ok) {
            int leader = __ffsll((long long)mask) - 1;
            int base = 0;
            if (lane == leader) base = atomicAdd(&bcnt, __popcll(mask));
            base = __shfl(base, leader);
            int off = __popcll(mask & ((1ull << lane) - 1ull));
            st[base + off] = ((unsigned int)r << 16) | (unsigned int)col[e];
            atomicAdd(&h[r], 1);  // LDS atomic
        }
    }
    __syncthreads();
    unsigned short* c = cnt + s * CSTRIDE + lo;
    for (int i = tid; i < RANGE; i += 1024) c[i] = (unsigned short)h[i];
    if (tid == 0) bsize[s * 8 + rng] = bcnt;
    // ----- independent side-job: fp32 emb -> fp8 mirror (1 iter/thread) -----
    for (int t = bid * 1024 + tid; t < NN * DIM / 8; t += 512 * 1024) {
        const float4* p = (const float4*)emb + t * 2;
        float4 a = p[0], b = p[1];
        uint2 pk;
        pk.x = enc4(a.x, a.y, a.z, a.w);
        pk.y = enc4(b.x, b.y, b.z, b.w);
        ((uint2*)x08)[t] = pk;
    }
}

// ---------------- rowscan + partial-sum fusion ----------------
__global__ __launch_bounds__(256) void k_rowscan(unsigned short* __restrict__ cnt,
                                                 int* __restrict__ deg,
                                                 int* __restrict__ partial) {
    __shared__ int sred[256];
    int t = threadIdx.x;
    int r = blockIdx.x * 256 + t;
    int acc = 0;
    if (r < NN) {
#pragma unroll
        for (int s = 0; s < NSL; ++s) {
            int c = cnt[s * CSTRIDE + r];
            cnt[s * CSTRIDE + r] = (unsigned short)acc;  // exclusive within-row offset
            acc += c;
        }
        deg[r] = acc;
    }
    sred[t] = acc;
    __syncthreads();
    for (int off = 128; off > 0; off >>= 1) {
        if (t < off) sred[t] += sred[t + off];
        __syncthreads();
    }
    if (t == 0) partial[blockIdx.x] = sred[0];
}

// ---------------- scan_final with inline top-scan ----------------
// Every block loads all 196 partials into LDS and computes its own prefix
// (replaces the separate k_scan_top dispatch — trivial redundant work).
__global__ __launch_bounds__(256) void k_scan_final(const int* __restrict__ deg,
                                                    const int* __restrict__ partial,
                                                    int* __restrict__ offs) {
    __shared__ int ps[256];
    __shared__ int s[256];
    int t = threadIdx.x;
    ps[t] = (t < NPARTS) ? partial[t] : 0;
    __syncthreads();
    for (int off = 1; off < 256; off <<= 1) {
        int x = (t >= off) ? ps[t - off] : 0;
        __syncthreads();
        ps[t] += x;
        __syncthreads();
    }
    int bpre = (blockIdx.x == 0) ? 0 : ps[blockIdx.x - 1];
    int i = blockIdx.x * 256 + t;
    int v = (i < NN) ? deg[i] : 0;
    s[t] = v;
    __syncthreads();
    for (int off = 1; off < 256; off <<= 1) {
        int x = (t >= off) ? s[t - off] : 0;
        __syncthreads();
        s[t] += x;
        __syncthreads();
    }
    int excl = s[t] - v;
    if (i <= NN) offs[i] = bpre + excl;  // offs[NN] = NE (total)
}

// ---------------- CSR fill from staged buckets (NO global atomics) ----------------
// bid -> s = bid>>3, rng = bid&7 (bid%8 == rng): all 64 blocks writing a
// range's csr region run on ONE XCD -> full-line evictions (WRITE ~5 MB).
// Reads ONLY its own staged bucket (~10 KB, L3-hot from k_hist).
__global__ __launch_bounds__(1024) void k_fillb(const unsigned int* __restrict__ stage,
                                                const int* __restrict__ bsize,
                                                const int* __restrict__ offs,
                                                const unsigned short* __restrict__ cnt,
                                                int* __restrict__ csr) {
    __shared__ int cur[RANGE];
    int bid = blockIdx.x;
    int s   = bid >> 3;
    int rng = bid & 7;
    int lo = rng * RANGE;
    int tid = threadIdx.x;
    const unsigned short* c = cnt + s * CSTRIDE + lo;
    const int* o = offs + lo;
    for (int i = tid; i < RANGE; i += 1024) cur[i] = o[i] + c[i];
    __syncthreads();
    int nb = bsize[s * 8 + rng];
    const unsigned int* st = stage + (size_t)(s * 8 + rng) * SLICEB;
    for (int i = tid; i < nb; i += 1024) {
        unsigned int pk = st[i];
        int r = pk >> 16;
        int pos = atomicAdd(&cur[r], 1);  // LDS atomic
        csr[pos] = (int)(pk & 0xffffu);
    }
}

// ---------------- one propagation layer (fp8 gather, fp32 accum) ----------------
// 8 nodes per wave: lane>>3 = node in wave, lane&7 = feature-octet.
// Gather source: fp8 mirror (3.2 MB, per-XCD-L2-resident, 64 B/edge).
// bf16 copies kept ONLY for final out-assembly (fp8 error doesn't compound).
template <int PHASE>
__global__ __launch_bounds__(256) void k_layer(const unsigned char* __restrict__ xin8,
                                               const float* __restrict__ emb,
                                               const unsigned short* __restrict__ xa16,
                                               const unsigned short* __restrict__ xb16,
                                               unsigned short* __restrict__ xout16,
                                               unsigned char* __restrict__ xout8,
                                               float* __restrict__ out,
                                               const int* __restrict__ offs,
                                               const int* __restrict__ csr) {
    int wid = (blockIdx.x * blockDim.x + threadIdx.x) >> 6;
    int lane = threadIdx.x & 63;
    int sub = lane >> 3;    // node within wave (0..7)
    int sl = lane & 7;      // feature-octet index (0..7)
    int n = 8 * wid + sub;
    if (n >= NN) return;
    int beg = offs[n];
    int end = offs[n + 1];
    const unsigned char* xq = xin8 + sl * 8;  // + c*64 bytes per neighbor

    float a0 = 0.f, a1 = 0.f, a2 = 0.f, a3 = 0.f, a4 = 0.f, a5 = 0.f, a6 = 0.f, a7 = 0.f;
    float b0 = 0.f, b1 = 0.f, b2 = 0.f, b3 = 0.f, b4 = 0.f, b5 = 0.f, b6 = 0.f, b7 = 0.f;
    int e = beg;
    for (; e + 8 <= end; e += 8) {
        int c0 = csr[e + 0], c1 = csr[e + 1], c2 = csr[e + 2], c3 = csr[e + 3];
        int c4 = csr[e + 4], c5 = csr[e + 5], c6 = csr[e + 6], c7 = csr[e + 7];
        uint2 u0 = *(const uint2*)(xq + c0 * 64);
        uint2 u1 = *(const uint2*)(xq + c1 * 64);
        uint2 u2 = *(const uint2*)(xq + c2 * 64);
        uint2 u3 = *(const uint2*)(xq + c3 * 64);
        uint2 u4 = *(const uint2*)(xq + c4 * 64);
        uint2 u5 = *(const uint2*)(xq + c5 * 64);
        uint2 u6 = *(const uint2*)(xq + c6 * 64);
        uint2 u7 = *(const uint2*)(xq + c7 * 64);
        f32x2 p;
        p = dec2<false>(u0.x); a0 += p[0]; a1 += p[1];
        p = dec2<true >(u0.x); a2 += p[0]; a3 += p[1];
        p = dec2<false>(u0.y); a4 += p[0]; a5 += p[1];
        p = dec2<true >(u0.y); a6 += p[0]; a7 += p[1];
        p = dec2<false>(u1.x); b0 += p[0]; b1 += p[1];
        p = dec2<true >(u1.x); b2 += p[0]; b3 += p[1];
        p = dec2<false>(u1.y); b4 += p[0]; b5 += p[1];
        p = dec2<true >(u1.y); b6 += p[0]; b7 += p[1];
        p = dec2<false>(u2.x); a0 += p[0]; a1 += p[1];
        p = dec2<true >(u2.x); a2 += p[0]; a3 += p[1];
        p = dec2<false>(u2.y); a4 += p[0]; a5 += p[1];
        p = dec2<true >(u2.y); a6 += p[0]; a7 += p[1];
        p = dec2<false>(u3.x); b0 += p[0]; b1 += p[1];
        p = dec2<true >(u3.x); b2 += p[0]; b3 += p[1];
        p = dec2<false>(u3.y); b4 += p[0]; b5 += p[1];
        p = dec2<true >(u3.y); b6 += p[0]; b7 += p[1];
        p = dec2<false>(u4.x); a0 += p[0]; a1 += p[1];
        p = dec2<true >(u4.x); a2 += p[0]; a3 += p[1];
        p = dec2<false>(u4.y); a4 += p[0]; a5 += p[1];
        p = dec2<true >(u4.y); a6 += p[0]; a7 += p[1];
        p = dec2<false>(u5.x); b0 += p[0]; b1 += p[1];
        p = dec2<true >(u5.x); b2 += p[0]; b3 += p[1];
        p = dec2<false>(u5.y); b4 += p[0]; b5 += p[1];
        p = dec2<true >(u5.y); b6 += p[0]; b7 += p[1];
        p = dec2<false>(u6.x); a0 += p[0]; a1 += p[1];
        p = dec2<true >(u6.x); a2 += p[0]; a3 += p[1];
        p = dec2<false>(u6.y); a4 += p[0]; a5 += p[1];
        p = dec2<true >(u6.y); a6 += p[0]; a7 += p[1];
        p = dec2<false>(u7.x); b0 += p[0]; b1 += p[1];
        p = dec2<true >(u7.x); b2 += p[0]; b3 += p[1];
        p = dec2<false>(u7.y); b4 += p[0]; b5 += p[1];
        p = dec2<true >(u7.y); b6 += p[0]; b7 += p[1];
    }
    for (; e < end; ++e) {
        uint2 u = *(const uint2*)(xq + csr[e] * 64);
        f32x2 p;
        p = dec2<false>(u.x); a0 += p[0]; a1 += p[1];
        p = dec2<true >(u.x); a2 += p[0]; a3 += p[1];
        p = dec2<false>(u.y); a4 += p[0]; a5 += p[1];
        p = dec2<true >(u.y); a6 += p[0]; a7 += p[1];
    }

    int d = end - beg;
    float inv = (d > 0) ? 1.0f / (float)d : 0.0f;
    float v0 = (a0 + b0) * inv;
    float v1 = (a1 + b1) * inv;
    float v2 = (a2 + b2) * inv;
    float v3 = (a3 + b3) * inv;
    float v4 = (a4 + b4) * inv;
    float v5 = (a5 + b5) * inv;
    float v6 = (a6 + b6) * inv;
    float v7 = (a7 + b7) * inv;

    int o = n * DIM + sl * 8;
    if (PHASE < 2) {
        uint4 pk16 = {(unsigned int)f2b(v0) | ((unsigned int)f2b(v1) << 16),
                      (unsigned int)f2b(v2) | ((unsigned int)f2b(v3) << 16),
                      (unsigned int)f2b(v4) | ((unsigned int)f2b(v5) << 16),
                      (unsigned int)f2b(v6) | ((unsigned int)f2b(v7) << 16)};
        *(uint4*)(xout16 + o) = pk16;
        uint2 pk8;
        pk8.x = enc4(v0, v1, v2, v3);
        pk8.y = enc4(v4, v5, v6, v7);
        *(uint2*)(xout8 + o) = pk8;
    } else {
        float4 e0 = *(const float4*)(emb + o);
        float4 e1 = *(const float4*)(emb + o + 4);
        uint4 ua = *(const uint4*)(xa16 + o);
        uint4 ub = *(const uint4*)(xb16 + o);
        float4 o0, o1;
        o0.x = 0.25f * (e0.x + blo(ua.x) + blo(ub.x) + v0);
        o0.y = 0.25f * (e0.y + bhi(ua.x) + bhi(ub.x) + v1);
        o0.z = 0.25f * (e0.z + blo(ua.y) + blo(ub.y) + v2);
        o0.w = 0.25f * (e0.w + bhi(ua.y) + bhi(ub.y) + v3);
        o1.x = 0.25f * (e1.x + blo(ua.z) + blo(ub.z) + v4);
        o1.y = 0.25f * (e1.y + bhi(ua.z) + bhi(ub.z) + v5);
        o1.z = 0.25f * (e1.z + blo(ua.w) + blo(ub.w) + v6);
        o1.w = 0.25f * (e1.w + bhi(ua.w) + bhi(ub.w) + v7);
        *(float4*)(out + o) = o0;
        *(float4*)(out + o + 4) = o1;
    }
}

extern "C" void kernel_launch(void* const* d_in, const int* in_sizes, int n_in,
                              void* d_out, int out_size, void* d_ws, size_t ws_size,
                              hipStream_t stream) {
    const int* edge = (const int*)d_in[0];
    const int* row = edge;        // edge_index[0]
    const int* col = edge + NE;   // edge_index[1]
    const float* emb = (const float*)d_in[1];
    float* out = (float*)d_out;

    // workspace layout (~75 MB of 256 MB)
    int* deg    = (int*)d_ws;                                // 50048 ints
    int* offs   = deg + 50048;                               // 50112 ints
    int* partial= offs + 50112;                              // 256 ints
    int* bsize  = partial + 256;                             // 512 ints (pad 576)
    int* csr    = bsize + 576;                               // 1250048 ints
    unsigned short* cnt = (unsigned short*)(csr + 1250048);  // 64*50048 ushort (6.4MB)
    unsigned short* xa16 = cnt + (size_t)NSL * CSTRIDE;      // 3.2M ushort
    unsigned short* xb16 = xa16 + NN * DIM;                  // 3.2M ushort
    unsigned char* x08 = (unsigned char*)(xb16 + NN * DIM);  // 3.2M bytes
    unsigned char* xa8 = x08 + NN * DIM;                     // 3.2M bytes
    unsigned char* xb8 = xa8 + NN * DIM;                     // 3.2M bytes
    unsigned int* stage = (unsigned int*)(xb8 + NN * DIM);   // 512*19532 uints (40MB)

    k_hist      <<<NSL * 8, 1024, 0, stream>>>(row, col, emb, x08, cnt, stage, bsize);
    k_rowscan   <<<NPARTS, 256, 0, stream>>>(cnt, deg, partial);
    k_scan_final<<<NPARTS, 256, 0, stream>>>(deg, partial, offs);
    k_fillb     <<<NSL * 8, 1024, 0, stream>>>(stage, bsize, offs, cnt, csr);

    // 8 nodes per wave: 6250 waves -> 1563 blocks of 256 (guard in-kernel)
    int layer_blocks = 1563;
    k_layer<0><<<layer_blocks, 256, 0, stream>>>(x08, nullptr, nullptr, nullptr, xa16, xa8, nullptr, offs, csr);
    k_layer<1><<<layer_blocks, 256, 0, stream>>>(xa8, nullptr, nullptr, nullptr, xb16, xb8, nullptr, offs, csr);
    k_layer<2><<<layer_blocks, 256, 0, stream>>>(xb8, emb, xa16, xb16, nullptr, nullptr, out, offs, csr);
}